// Round 1
// baseline (583.700 us; speedup 1.0000x reference)
//
#include <hip/hip_runtime.h>
#include <hip/hip_bf16.h>
#include <math.h>

// Problem constants: B=4, T=512, S=1024, H=768, V=50257
#define BB 4
#define TT 512
#define SS 1024
#define HH 768
#define VV 50257
#define NW 1571            // ceil(V/32) bitmap words per batch
#define NWP 1600           // padded stride for bm_g/pre_g
#define NPROJ 1536         // proj blocks (6144 rows / 4 waves)
#define NLB 128            // padded words per dirty-line bitmap variant (need 99)

// ---------------------------------------------------------------------------
// Kernel P (fused prep): blocks [0,1536) do projections; blocks [1536,1540)
// do per-batch bitmap/rank setup PLUS dirty-64B-line structures for the four
// logits-alignment variants (head = (4 - row%4)&3 floats).
// ---------------------------------------------------------------------------
__global__ __launch_bounds__(256) void prep_kernel(
    const float* __restrict__ src, const float* __restrict__ tgt,
    const float* __restrict__ W, const float* __restrict__ bptr,
    const int* __restrict__ ids,
    float* __restrict__ src_proj, float* __restrict__ tgt_proj,
    unsigned* __restrict__ bm_g, unsigned* __restrict__ pre_g,
    unsigned* __restrict__ lbm_g, unsigned* __restrict__ dllc_g,
    unsigned short* __restrict__ rank_g, unsigned short* __restrict__ dll_g)
{
    __shared__ unsigned bm[NW];
    __shared__ unsigned pre[NW];
    __shared__ unsigned scan[256];
    __shared__ unsigned lbm[4 * NLB];
    __shared__ unsigned dcnt[4];
    const int tid = threadIdx.x;

    if (blockIdx.x < NPROJ) {
        // ---- projection role: one wave per row, 4 rows/block ----
        const int wave = tid >> 6;
        const int lane = tid & 63;
        const int row  = blockIdx.x * 4 + wave;   // 0 .. 6143

        const float* vec;
        const float* w;
        if (row < BB * SS) { vec = src + (size_t)row * HH;            w = W; }
        else               { vec = tgt + (size_t)(row - BB*SS) * HH;  w = W + HH; }
        const float4* v4 = (const float4*)vec;
        const float4* w4 = (const float4*)w;

        float acc = 0.f;
#pragma unroll
        for (int k = 0; k < 3; ++k) {
            float4 a = v4[k * 64 + lane];
            float4 b = w4[k * 64 + lane];
            acc += a.x * b.x + a.y * b.y + a.z * b.z + a.w * b.w;
        }
#pragma unroll
        for (int off = 32; off > 0; off >>= 1) acc += __shfl_down(acc, off);
        if (lane == 0) {
            if (row < BB * SS) src_proj[row] = acc;
            else               tgt_proj[row - BB * SS] = acc + bptr[0];
        }
        return;
    }

    // ---- setup role: one block per batch ----
    const int b = blockIdx.x - NPROJ;

    for (int i = tid; i < NW; i += 256) bm[i] = 0u;
    __syncthreads();
    const int* idb = ids + b * SS;
    for (int s = tid; s < SS; s += 256) {
        const int v = idb[s];
        atomicOr(&bm[v >> 5], 1u << (v & 31));
    }
    __syncthreads();

    unsigned cnt[7];
    unsigned local = 0;
    const int w0 = tid * 7;                 // 256*7 = 1792 >= 1571
#pragma unroll
    for (int k = 0; k < 7; ++k) {
        const int w = w0 + k;
        cnt[k] = local;
        local += (w < NW) ? (unsigned)__popc(bm[w]) : 0u;
    }
    scan[tid] = local;
    __syncthreads();
    for (int off = 1; off < 256; off <<= 1) {
        const unsigned mine = scan[tid];
        const unsigned add  = (tid >= off) ? scan[tid - off] : 0u;
        __syncthreads();
        scan[tid] = mine + add;
        __syncthreads();
    }
    const unsigned excl = (tid > 0) ? scan[tid - 1] : 0u;
#pragma unroll
    for (int k = 0; k < 7; ++k) {
        const int w = w0 + k;
        if (w < NW) {
            const unsigned p = excl + cnt[k];
            pre[w] = p;
            pre_g[b * NWP + w] = p;
            bm_g[b * NWP + w]  = bm[w];
        }
    }
    __syncthreads();
    for (int s = tid; s < SS; s += 256) {
        const int v = idb[s];
        const unsigned w = (unsigned)v >> 5, bit = (unsigned)v & 31u;
        const unsigned r = pre[w] + (unsigned)__popc(bm[w] & ((1u << bit) - 1u));
        rank_g[b * SS + s] = (unsigned short)r;
    }

    // ---- dirty-64B-line bitmap + list, 4 alignment variants ----
    for (int i = tid; i < 4 * NLB; i += 256) lbm[i] = 0u;
    if (tid < 4) dcnt[tid] = 0u;
    __syncthreads();
    for (int s = tid; s < SS; s += 256) {
        const int v = idb[s];
#pragma unroll
        for (int h = 0; h < 4; ++h) {
            if (v >= h) {
                const int m = (v - h) >> 4;      // 16 floats per 64B line
                atomicOr(&lbm[(h << 7) + (m >> 5)], 1u << (m & 31));
            }
        }
    }
    __syncthreads();
    for (int w = tid; w < 4 * NLB; w += 256) {
        const unsigned word = lbm[w];
        const int h  = w >> 7;
        const int wi = w & (NLB - 1);
        lbm_g[(b * 4 + h) * NLB + wi] = word;
        if (word) {
            const int n = __popc(word);
            unsigned base = atomicAdd(&dcnt[h], (unsigned)n);
            unsigned x = word;
            while (x) {
                const int bit = __ffs(x) - 1;
                dll_g[(size_t)(b * 4 + h) * 1024 + base++] =
                    (unsigned short)((wi << 5) + bit);
                x &= x - 1u;
            }
        }
    }
    __syncthreads();
    if (tid < 4) dllc_g[b * 4 + tid] = dcnt[tid];
}

__device__ __forceinline__ float lut1(int v, const unsigned* bm,
                                      const unsigned* pre, const float* vals)
{
    const unsigned w = bm[v >> 5];
    const unsigned bit = (unsigned)v & 31u;
    if ((w >> bit) & 1u)
        return vals[pre[v >> 5] + (unsigned)__popc(w & ((1u << bit) - 1u))];
    return 0.f;
}

// ---------------------------------------------------------------------------
// Kernel B: one block per (b,t) row. Single-touch streaming write, plain
// stores, now split into two ADDRESS-DISJOINT phases (no ordering barrier,
// every 64B line written exactly once, fully):
//   pass 1 : vals[rank[s]] += attn[row,s] (LDS atomics) + p_gen (unchanged)
//   phase A: dense LUT write of FULL dirty 64B lines (4 lanes/line) from the
//            per-batch precomputed dirty-line list for this row's alignment.
//   phase B: pure zero stream over all float4 groups, skipping dirty lines
//            with one broadcast LDS bit-test (~8 inst / 16B, constant data).
// ---------------------------------------------------------------------------
__global__ __launch_bounds__(256) void row_kernel(
    const float* __restrict__ attn,
    const float* __restrict__ src_proj,
    const float* __restrict__ tgt_proj,
    const unsigned* __restrict__ bm_g,
    const unsigned* __restrict__ pre_g,
    const unsigned* __restrict__ lbm_g,
    const unsigned* __restrict__ dllc_g,
    const unsigned short* __restrict__ rank_g,
    const unsigned short* __restrict__ dll_g,
    float* __restrict__ out)
{
    __shared__ unsigned bm[NW];
    __shared__ unsigned pre[NW];
    __shared__ float vals[SS];
    __shared__ float wsum[4];
    __shared__ unsigned lbm_s[NLB];

    const int row = blockIdx.x;     // 0 .. B*T-1
    const int b   = row >> 9;       // T = 512
    const int tid = threadIdx.x;

    float* logits = out + (BB * TT) + (size_t)row * VV;
    const int head = (int)(((16u - (unsigned)((uintptr_t)logits & 15u)) & 15u) >> 2);

    for (int i = tid; i < NW; i += 256) { bm[i] = bm_g[b*NWP+i]; pre[i] = pre_g[b*NWP+i]; }
    if (tid < NLB) lbm_s[tid] = lbm_g[(b * 4 + head) * NLB + tid];
    ((float4*)vals)[tid] = make_float4(0.f, 0.f, 0.f, 0.f);
    __syncthreads();

    // ---- pass 1: vals accumulate + p_gen dot (1024 = 4*256, vectorized) ----
    const float4*  a4p = (const float4*)(attn + (size_t)row * SS);
    const float4*  sp4 = (const float4*)(src_proj + b * SS);
    const ushort4* r4p = (const ushort4*)(rank_g + b * SS);
    const float4  a = a4p[tid];
    const float4  p = sp4[tid];
    const ushort4 r = r4p[tid];
    atomicAdd(&vals[r.x], a.x);
    atomicAdd(&vals[r.y], a.y);
    atomicAdd(&vals[r.z], a.z);
    atomicAdd(&vals[r.w], a.w);
    float acc = a.x * p.x + a.y * p.y + a.z * p.z + a.w * p.w;
#pragma unroll
    for (int off = 32; off > 0; off >>= 1) acc += __shfl_down(acc, off);
    if ((tid & 63) == 0) wsum[tid >> 6] = acc;
    __syncthreads();   // vals final + wsum visible
    if (tid == 0) {
        const float x = wsum[0] + wsum[1] + wsum[2] + wsum[3] + tgt_proj[row];
        out[row] = 1.f / (1.f + expf(-x));
    }

    const int n4 = (VV - head) >> 2;
    float4* p4 = (float4*)(logits + head);

    // ---- phase A: full dirty 64B lines, dense LUT work (4 lanes per line) --
    const int dn = (int)dllc_g[b * 4 + head];
    const unsigned short* dll = dll_g + (size_t)(b * 4 + head) * 1024;
    for (int j = tid; j < dn * 4; j += 256) {
        const int m = (int)dll[j >> 2];
        const int g = (m << 2) + (j & 3);
        if (g < n4) {
            const int v0 = head + (g << 2);
            float4 o;
            o.x = lut1(v0,     bm, pre, vals);
            o.y = lut1(v0 + 1, bm, pre, vals);
            o.z = lut1(v0 + 2, bm, pre, vals);
            o.w = lut1(v0 + 3, bm, pre, vals);
            p4[g] = o;
        }
    }

    // ---- phase B: zero stream over clean lines (disjoint from phase A) ----
    const float4 z4 = make_float4(0.f, 0.f, 0.f, 0.f);
    for (int i = tid; i < n4; i += 256) {
        const int line = i >> 2;
        if (!((lbm_s[line >> 5] >> (line & 31)) & 1u))
            p4[i] = z4;
    }

    // ---- head / tail (lut writes, < 4 elements each) ----
    if (tid < head) logits[tid] = lut1(tid, bm, pre, vals);
    const int done = head + (n4 << 2);
    for (int v = done + tid; v < VV; v += 256)
        logits[v] = lut1(v, bm, pre, vals);
}

extern "C" void kernel_launch(void* const* d_in, const int* in_sizes, int n_in,
                              void* d_out, int out_size, void* d_ws, size_t ws_size,
                              hipStream_t stream) {
    const int*   ids  = (const int*)d_in[0];    // [B,S]
    const float* attn = (const float*)d_in[1];  // [B,T,S]
    const float* src  = (const float*)d_in[2];  // [B,S,H]
    const float* tgt  = (const float*)d_in[3];  // [B,T,H]
    const float* W    = (const float*)d_in[4];  // [2H,1]
    const float* bp   = (const float*)d_in[5];  // [1]

    float* out = (float*)d_out;                 // [B*T (p_gen) | B*T*V]

    // ws layout (all 16B-aligned)
    float*          src_proj = (float*)d_ws;                        // 4096 f
    float*          tgt_proj = src_proj + BB * SS;                  // 2048 f
    unsigned*       bm_g     = (unsigned*)(tgt_proj + BB * TT);     // B*NWP u32
    unsigned*       pre_g    = bm_g + BB * NWP;                     // B*NWP u32
    unsigned*       lbm_g    = pre_g + BB * NWP;                    // B*4*NLB u32
    unsigned*       dllc_g   = lbm_g + BB * 4 * NLB;                // 16 u32
    unsigned short* rank_g   = (unsigned short*)(dllc_g + 16);      // B*S u16
    unsigned short* dll_g    = rank_g + BB * SS;                    // B*4*1024 u16

    prep_kernel<<<NPROJ + BB, 256, 0, stream>>>(
        src, tgt, W, bp, ids, src_proj, tgt_proj, bm_g, pre_g,
        lbm_g, dllc_g, rank_g, dll_g);
    row_kernel<<<BB * TT, 256, 0, stream>>>(
        attn, src_proj, tgt_proj, bm_g, pre_g, lbm_g, dllc_g,
        rank_g, dll_g, out);
}

// Round 3
// 520.278 us; speedup vs baseline: 1.1219x; 1.1219x over previous
//
#include <hip/hip_runtime.h>
#include <hip/hip_bf16.h>
#include <math.h>

// Problem constants: B=4, T=512, S=1024, H=768, V=50257
#define BB 4
#define TT 512
#define SS 1024
#define HH 768
#define VV 50257
#define NW 1571            // ceil(V/32) bitmap words per batch
#define NWP 1600           // padded stride for bm_g/pre_g
#define NPROJ 1536         // proj blocks (6144 rows / 4 waves)
#define NLB 128            // padded words per dirty-line bitmap variant (need 99)
#define NVAR 16            // 64B-alignment variants (row stride % 16 == 1)

// ---------------------------------------------------------------------------
// Kernel P (fused prep): blocks [0,1536) do projections; blocks [1536,1540)
// do per-batch bitmap/rank setup PLUS dirty-PHYSICAL-64B-line structures for
// all 16 base-alignment variants phi (line k of variant phi covers floats
// [16k-phi, 16k+16-phi) of the row — 64B-aligned in memory).
// ---------------------------------------------------------------------------
__global__ __launch_bounds__(256) void prep_kernel(
    const float* __restrict__ src, const float* __restrict__ tgt,
    const float* __restrict__ W, const float* __restrict__ bptr,
    const int* __restrict__ ids,
    float* __restrict__ src_proj, float* __restrict__ tgt_proj,
    unsigned* __restrict__ bm_g, unsigned* __restrict__ pre_g,
    unsigned* __restrict__ lbm_g, unsigned* __restrict__ dllc_g,
    unsigned short* __restrict__ rank_g, unsigned short* __restrict__ dll_g)
{
    __shared__ unsigned bm[NW];
    __shared__ unsigned pre[NW];
    __shared__ unsigned scan[256];
    __shared__ unsigned lbm[NVAR * NLB];
    __shared__ unsigned dcnt[NVAR];
    const int tid = threadIdx.x;

    if (blockIdx.x < NPROJ) {
        // ---- projection role: one wave per row, 4 rows/block ----
        const int wave = tid >> 6;
        const int lane = tid & 63;
        const int row  = blockIdx.x * 4 + wave;   // 0 .. 6143

        const float* vec;
        const float* w;
        if (row < BB * SS) { vec = src + (size_t)row * HH;            w = W; }
        else               { vec = tgt + (size_t)(row - BB*SS) * HH;  w = W + HH; }
        const float4* v4 = (const float4*)vec;
        const float4* w4 = (const float4*)w;

        float acc = 0.f;
#pragma unroll
        for (int k = 0; k < 3; ++k) {
            float4 a = v4[k * 64 + lane];
            float4 b = w4[k * 64 + lane];
            acc += a.x * b.x + a.y * b.y + a.z * b.z + a.w * b.w;
        }
#pragma unroll
        for (int off = 32; off > 0; off >>= 1) acc += __shfl_down(acc, off);
        if (lane == 0) {
            if (row < BB * SS) src_proj[row] = acc;
            else               tgt_proj[row - BB * SS] = acc + bptr[0];
        }
        return;
    }

    // ---- setup role: one block per batch ----
    const int b = blockIdx.x - NPROJ;

    for (int i = tid; i < NW; i += 256) bm[i] = 0u;
    __syncthreads();
    const int* idb = ids + b * SS;
    for (int s = tid; s < SS; s += 256) {
        const int v = idb[s];
        atomicOr(&bm[v >> 5], 1u << (v & 31));
    }
    __syncthreads();

    unsigned cnt[7];
    unsigned local = 0;
    const int w0 = tid * 7;                 // 256*7 = 1792 >= 1571
#pragma unroll
    for (int k = 0; k < 7; ++k) {
        const int w = w0 + k;
        cnt[k] = local;
        local += (w < NW) ? (unsigned)__popc(bm[w]) : 0u;
    }
    scan[tid] = local;
    __syncthreads();
    for (int off = 1; off < 256; off <<= 1) {
        const unsigned mine = scan[tid];
        const unsigned add  = (tid >= off) ? scan[tid - off] : 0u;
        __syncthreads();
        scan[tid] = mine + add;
        __syncthreads();
    }
    const unsigned excl = (tid > 0) ? scan[tid - 1] : 0u;
#pragma unroll
    for (int k = 0; k < 7; ++k) {
        const int w = w0 + k;
        if (w < NW) {
            const unsigned p = excl + cnt[k];
            pre[w] = p;
            pre_g[b * NWP + w] = p;
            bm_g[b * NWP + w]  = bm[w];
        }
    }
    __syncthreads();
    for (int s = tid; s < SS; s += 256) {
        const int v = idb[s];
        const unsigned w = (unsigned)v >> 5, bit = (unsigned)v & 31u;
        const unsigned r = pre[w] + (unsigned)__popc(bm[w] & ((1u << bit) - 1u));
        rank_g[b * SS + s] = (unsigned short)r;
    }

    // ---- dirty-64B-line bitmap + list, 16 physical-alignment variants ----
    for (int i = tid; i < NVAR * NLB; i += 256) lbm[i] = 0u;
    if (tid < NVAR) dcnt[tid] = 0u;
    __syncthreads();
    for (int s = tid; s < SS; s += 256) {
        const int v = idb[s];
#pragma unroll
        for (int h = 0; h < NVAR; ++h) {
            const int m = (v + h) >> 4;      // physical line index for variant h
            atomicOr(&lbm[(h << 7) + (m >> 5)], 1u << (m & 31));
        }
    }
    __syncthreads();
    for (int w = tid; w < NVAR * NLB; w += 256) {
        const unsigned word = lbm[w];
        const int h  = w >> 7;
        const int wi = w & (NLB - 1);
        lbm_g[(b * NVAR + h) * NLB + wi] = word;
        if (word) {
            const int n = __popc(word);
            unsigned base = atomicAdd(&dcnt[h], (unsigned)n);
            unsigned x = word;
            while (x) {
                const int bit = __ffs(x) - 1;
                dll_g[(size_t)(b * NVAR + h) * 1024 + base++] =
                    (unsigned short)((wi << 5) + bit);
                x &= x - 1u;
            }
        }
    }
    __syncthreads();
    if (tid < NVAR) dllc_g[b * NVAR + tid] = dcnt[tid];
}

__device__ __forceinline__ float lut1(int v, const unsigned* bm,
                                      const unsigned* pre, const float* vals)
{
    const unsigned w = bm[v >> 5];
    const unsigned bit = (unsigned)v & 31u;
    if ((w >> bit) & 1u)
        return vals[pre[v >> 5] + (unsigned)__popc(w & ((1u << bit) - 1u))];
    return 0.f;
}

// ---------------------------------------------------------------------------
// Kernel B: one block per (b,t) row. Two ADDRESS-DISJOINT phases over
// PHYSICAL 64B lines (every line written exactly once, fully, aligned):
//   pass 1 : vals[rank[s]] += attn[row,s] (LDS atomics) + p_gen (unchanged)
//   phase A: dirty lines from the per-batch list for this row's phi variant;
//            4 lanes/line write full 64B via lut (zeros inside line included).
//   phase B: pure zero stream over clean full lines — 1 broadcast LDS bit
//            test + 1 aligned float4 store per 16B; no lut, no data deps.
//   head/tail: <16 floats each, scalar lut writes.
// ---------------------------------------------------------------------------
__global__ __launch_bounds__(256) void row_kernel(
    const float* __restrict__ attn,
    const float* __restrict__ src_proj,
    const float* __restrict__ tgt_proj,
    const unsigned* __restrict__ bm_g,
    const unsigned* __restrict__ pre_g,
    const unsigned* __restrict__ lbm_g,
    const unsigned* __restrict__ dllc_g,
    const unsigned short* __restrict__ rank_g,
    const unsigned short* __restrict__ dll_g,
    float* __restrict__ out)
{
    __shared__ unsigned bm[NW];
    __shared__ unsigned pre[NW];
    __shared__ float vals[SS];
    __shared__ float wsum[4];
    __shared__ unsigned lbm_s[NLB];

    const int row = blockIdx.x;     // 0 .. B*T-1
    const int b   = row >> 9;       // T = 512
    const int tid = threadIdx.x;

    float* logits = out + (BB * TT) + (size_t)row * VV;
    // phi = float offset of row base inside its physical 64B line
    const int phi = (int)(((uintptr_t)logits >> 2) & 15u);

    for (int i = tid; i < NW; i += 256) { bm[i] = bm_g[b*NWP+i]; pre[i] = pre_g[b*NWP+i]; }
    if (tid < NLB) lbm_s[tid] = lbm_g[(b * NVAR + phi) * NLB + tid];
    ((float4*)vals)[tid] = make_float4(0.f, 0.f, 0.f, 0.f);
    __syncthreads();

    // ---- pass 1: vals accumulate + p_gen dot (1024 = 4*256, vectorized) ----
    const float4*  a4p = (const float4*)(attn + (size_t)row * SS);
    const float4*  sp4 = (const float4*)(src_proj + b * SS);
    const ushort4* r4p = (const ushort4*)(rank_g + b * SS);
    const float4  a = a4p[tid];
    const float4  p = sp4[tid];
    const ushort4 r = r4p[tid];
    atomicAdd(&vals[r.x], a.x);
    atomicAdd(&vals[r.y], a.y);
    atomicAdd(&vals[r.z], a.z);
    atomicAdd(&vals[r.w], a.w);
    float acc = a.x * p.x + a.y * p.y + a.z * p.z + a.w * p.w;
#pragma unroll
    for (int off = 32; off > 0; off >>= 1) acc += __shfl_down(acc, off);
    if ((tid & 63) == 0) wsum[tid >> 6] = acc;
    __syncthreads();   // vals final + wsum visible
    if (tid == 0) {
        const float x = wsum[0] + wsum[1] + wsum[2] + wsum[3] + tgt_proj[row];
        out[row] = 1.f / (1.f + expf(-x));
    }

    // full lines are k in [k_min, k_lim): floats [16k-phi, 16k+16-phi)
    const int k_lim = (VV + phi) >> 4;
    const int k_min = (phi > 0) ? 1 : 0;

    // ---- phase A: dirty physical 64B lines, full-line LUT writes ----------
    const int dn = (int)dllc_g[b * NVAR + phi];
    const unsigned short* dll = dll_g + (size_t)(b * NVAR + phi) * 1024;
    for (int j = tid; j < dn * 4; j += 256) {
        const int k = (int)dll[j >> 2];
        if (k >= k_min && k < k_lim) {
            const int v0 = (k << 4) - phi + ((j & 3) << 2);
            float4 o;
            o.x = lut1(v0,     bm, pre, vals);
            o.y = lut1(v0 + 1, bm, pre, vals);
            o.z = lut1(v0 + 2, bm, pre, vals);
            o.w = lut1(v0 + 3, bm, pre, vals);
            *(float4*)(logits + v0) = o;      // 64B-line aligned, 16B store
        }
    }

    // ---- phase B: zero stream over clean full lines (disjoint from A) -----
    const float4 z4 = make_float4(0.f, 0.f, 0.f, 0.f);
    const int ng = (k_lim - k_min) << 2;      // float4 groups in full-line space
    const int c0 = (k_min << 4) - phi;        // float offset of first full line
    for (int g = tid; g < ng; g += 256) {
        const int line = k_min + (g >> 2);
        if (!((lbm_s[line >> 5] >> (line & 31)) & 1u))
            *(float4*)(logits + c0 + (g << 2)) = z4;
    }

    // ---- head / tail (scalar lut writes, < 16 elements each) --------------
    const int hn = (16 - phi) & 15;           // floats before first full line
    if (tid < hn) logits[tid] = lut1(tid, bm, pre, vals);
    const int t0 = (k_lim << 4) - phi;        // first float after last full line
    if (t0 + tid < VV) logits[t0 + tid] = lut1(t0 + tid, bm, pre, vals);
}

extern "C" void kernel_launch(void* const* d_in, const int* in_sizes, int n_in,
                              void* d_out, int out_size, void* d_ws, size_t ws_size,
                              hipStream_t stream) {
    const int*   ids  = (const int*)d_in[0];    // [B,S]
    const float* attn = (const float*)d_in[1];  // [B,T,S]
    const float* src  = (const float*)d_in[2];  // [B,S,H]
    const float* tgt  = (const float*)d_in[3];  // [B,T,H]
    const float* W    = (const float*)d_in[4];  // [2H,1]
    const float* bp   = (const float*)d_in[5];  // [1]

    float* out = (float*)d_out;                 // [B*T (p_gen) | B*T*V]

    // ws layout (all 16B-aligned)
    float*          src_proj = (float*)d_ws;                        // 4096 f
    float*          tgt_proj = src_proj + BB * SS;                  // 2048 f
    unsigned*       bm_g     = (unsigned*)(tgt_proj + BB * TT);     // B*NWP u32
    unsigned*       pre_g    = bm_g + BB * NWP;                     // B*NWP u32
    unsigned*       lbm_g    = pre_g + BB * NWP;                    // B*16*NLB u32
    unsigned*       dllc_g   = lbm_g + BB * NVAR * NLB;             // 64 u32
    unsigned short* rank_g   = (unsigned short*)(dllc_g + BB*NVAR); // B*S u16
    unsigned short* dll_g    = rank_g + BB * SS;                    // B*16*1024 u16

    prep_kernel<<<NPROJ + BB, 256, 0, stream>>>(
        src, tgt, W, bp, ids, src_proj, tgt_proj, bm_g, pre_g,
        lbm_g, dllc_g, rank_g, dll_g);
    row_kernel<<<BB * TT, 256, 0, stream>>>(
        attn, src_proj, tgt_proj, bm_g, pre_g, lbm_g, dllc_g,
        rank_g, dll_g, out);
}

// Round 4
// 465.554 us; speedup vs baseline: 1.2538x; 1.1175x over previous
//
#include <hip/hip_runtime.h>
#include <math.h>

// Problem constants: B=4, T=512, S=1024, H=768, V=50257
#define BB 4
#define TT 512
#define SS 1024
#define HH 768
#define VV 50257
#define NW 1571            // ceil(V/32) bitmap words per batch
#define NWP 1600           // uint2 stride per batch for bmpre_g (>= NW+1)
#define NPROJ 1536         // proj blocks (6144 rows / 4 waves)
#define KPB 257            // row-blocks per batch: 255 pairs + 2 singles

// ---------------------------------------------------------------------------
// Kernel P (fused prep): blocks [0,1536) do projections; blocks [1536,1540)
// do per-batch bitmap/rank setup. bm and pre are written INTERLEAVED as
// uint2 (one ds_read_b64 fetches both in the row kernel). Sentinel word at
// index NW is zeroed (row kernel may read w+1 == NW).
// ---------------------------------------------------------------------------
__global__ __launch_bounds__(256) void prep_kernel(
    const float* __restrict__ src, const float* __restrict__ tgt,
    const float* __restrict__ W, const float* __restrict__ bptr,
    const int* __restrict__ ids,
    float* __restrict__ src_proj, float* __restrict__ tgt_proj,
    uint2* __restrict__ bmpre_g, unsigned short* __restrict__ rank_g)
{
    __shared__ unsigned bm[NW];
    __shared__ unsigned pre[NW];
    __shared__ unsigned scan[256];
    const int tid = threadIdx.x;

    if (blockIdx.x < NPROJ) {
        // ---- projection role: one wave per row, 4 rows/block ----
        const int wave = tid >> 6;
        const int lane = tid & 63;
        const int row  = blockIdx.x * 4 + wave;   // 0 .. 6143

        const float* vec;
        const float* w;
        if (row < BB * SS) { vec = src + (size_t)row * HH;            w = W; }
        else               { vec = tgt + (size_t)(row - BB*SS) * HH;  w = W + HH; }
        const float4* v4 = (const float4*)vec;
        const float4* w4 = (const float4*)w;

        float acc = 0.f;
#pragma unroll
        for (int k = 0; k < 3; ++k) {
            float4 a = v4[k * 64 + lane];
            float4 b = w4[k * 64 + lane];
            acc += a.x * b.x + a.y * b.y + a.z * b.z + a.w * b.w;
        }
#pragma unroll
        for (int off = 32; off > 0; off >>= 1) acc += __shfl_down(acc, off);
        if (lane == 0) {
            if (row < BB * SS) src_proj[row] = acc;
            else               tgt_proj[row - BB * SS] = acc + bptr[0];
        }
        return;
    }

    // ---- setup role: one block per batch ----
    const int b = blockIdx.x - NPROJ;

    for (int i = tid; i < NW; i += 256) bm[i] = 0u;
    __syncthreads();
    const int* idb = ids + b * SS;
    for (int s = tid; s < SS; s += 256) {
        const int v = idb[s];
        atomicOr(&bm[v >> 5], 1u << (v & 31));
    }
    __syncthreads();

    unsigned cnt[7];
    unsigned local = 0;
    const int w0 = tid * 7;                 // 256*7 = 1792 >= 1571
#pragma unroll
    for (int k = 0; k < 7; ++k) {
        const int w = w0 + k;
        cnt[k] = local;
        local += (w < NW) ? (unsigned)__popc(bm[w]) : 0u;
    }
    scan[tid] = local;
    __syncthreads();
    for (int off = 1; off < 256; off <<= 1) {
        const unsigned mine = scan[tid];
        const unsigned add  = (tid >= off) ? scan[tid - off] : 0u;
        __syncthreads();
        scan[tid] = mine + add;
        __syncthreads();
    }
    const unsigned excl = (tid > 0) ? scan[tid - 1] : 0u;
#pragma unroll
    for (int k = 0; k < 7; ++k) {
        const int w = w0 + k;
        if (w < NW) {
            const unsigned p = excl + cnt[k];
            pre[w] = p;
            bmpre_g[b * NWP + w] = make_uint2(bm[w], p);
        }
    }
    if (tid == 0) bmpre_g[b * NWP + NW] = make_uint2(0u, 0u);  // sentinel
    __syncthreads();
    for (int s = tid; s < SS; s += 256) {
        const int v = idb[s];
        const unsigned w = (unsigned)v >> 5, bit = (unsigned)v & 31u;
        const unsigned r = pre[w] + (unsigned)__popc(bm[w] & ((1u << bit) - 1u));
        rank_g[b * SS + s] = (unsigned short)r;
    }
}

// lut for one vocab index u: returns (row_a_val, row_b_val) or zeros.
__device__ __forceinline__ float2 lut2(int u, const uint2* __restrict__ bmpre,
                                       const float2* __restrict__ vals2)
{
    const uint2 bp = bmpre[u >> 5];
    const unsigned bt = (unsigned)u & 31u;
    if ((bp.x >> bt) & 1u)
        return vals2[bp.y + (unsigned)__popc(bp.x & ((1u << bt) - 1u))];
    return make_float2(0.f, 0.f);
}

// one element of the shared 5-wide window; t = s + j, word = w (+1 if t>=32)
#define ELEM(J, DST)                                                        \
    if (m5 & (1u << (J))) {                                                 \
        const unsigned t  = (unsigned)s + (J);                              \
        const unsigned bw = (t >= 32u) ? bp1.x : bp0.x;                     \
        const unsigned pw = (t >= 32u) ? bp1.y : bp0.y;                     \
        const unsigned bt = t & 31u;                                        \
        DST = vals2[pw + (unsigned)__popc(bw & ((1u << bt) - 1u))];         \
    }

// ---------------------------------------------------------------------------
// Kernel B: one block per ROW PAIR (2k+1, 2k+2) of a batch (255 pairs) plus
// two single-row blocks (rows 0, 511). Pair trick: row base mod 4 floats ==
// row mod 4, so head_b == head_a - 1 and both rows' aligned float4 groups
// come from ONE shared 5-element vocab window [v-1, v+3]:
//   1 shared ds_read_b64 (bm|pre interleaved) + 5 shared index computations
//   -> 2 aligned float4 stores.  vals interleaved per-rank as float2 so one
//   masked b64 read yields both rows' substituted values.
// Contiguous single-touch streams per row (R3 lesson: never scatter stores).
// ---------------------------------------------------------------------------
__global__ __launch_bounds__(256) void row_kernel(
    const float* __restrict__ attn,
    const float* __restrict__ src_proj,
    const float* __restrict__ tgt_proj,
    const uint2* __restrict__ bmpre_g,
    const unsigned short* __restrict__ rank_g,
    float* __restrict__ out)
{
    __shared__ uint2  bmpre[NW + 1];
    __shared__ float2 vals2[SS];
    __shared__ float  wsa[4], wsb[4];

    const int tid   = threadIdx.x;
    const int bid   = blockIdx.x;
    const int batch = bid / KPB;
    const int k     = bid - batch * KPB;
    const bool pair = (k > 0) && (k < 256);
    int row_a;
    if (k == 0)        row_a = batch * TT;            // single: row 0
    else if (k == 256) row_a = batch * TT + 511;      // single: row 511
    else               row_a = batch * TT + 2 * k - 1; // pair (odd, even)
    const int row_b = pair ? row_a + 1 : row_a;

    // ---- prologue: metadata + zeroed vals ----
    for (int i = tid; i < NW + 1; i += 256) bmpre[i] = bmpre_g[batch * NWP + i];
    ((float4*)vals2)[tid]       = make_float4(0.f, 0.f, 0.f, 0.f);
    ((float4*)vals2)[tid + 256] = make_float4(0.f, 0.f, 0.f, 0.f);
    __syncthreads();

    // ---- pass 1: vals2 accumulate + p_gen dots (ranks shared per batch) ----
    const float4*  aA  = (const float4*)(attn + (size_t)row_a * SS);
    const float4*  aB  = (const float4*)(attn + (size_t)row_b * SS);
    const float4*  sp4 = (const float4*)(src_proj + batch * SS);
    const ushort4* r4p = (const ushort4*)(rank_g + batch * SS);
    const float4  va = aA[tid];
    const float4  p  = sp4[tid];
    const ushort4 r  = r4p[tid];
    atomicAdd(&vals2[r.x].x, va.x);
    atomicAdd(&vals2[r.y].x, va.y);
    atomicAdd(&vals2[r.z].x, va.z);
    atomicAdd(&vals2[r.w].x, va.w);
    float accA = va.x * p.x + va.y * p.y + va.z * p.z + va.w * p.w;
    float accB = 0.f;
    if (pair) {
        const float4 vb = aB[tid];
        atomicAdd(&vals2[r.x].y, vb.x);
        atomicAdd(&vals2[r.y].y, vb.y);
        atomicAdd(&vals2[r.z].y, vb.z);
        atomicAdd(&vals2[r.w].y, vb.w);
        accB = vb.x * p.x + vb.y * p.y + vb.z * p.z + vb.w * p.w;
    }
#pragma unroll
    for (int off = 32; off > 0; off >>= 1) {
        accA += __shfl_down(accA, off);
        accB += __shfl_down(accB, off);
    }
    if ((tid & 63) == 0) { wsa[tid >> 6] = accA; wsb[tid >> 6] = accB; }
    __syncthreads();   // vals2 final + wsa/wsb visible
    if (tid == 0) {
        const float x = wsa[0] + wsa[1] + wsa[2] + wsa[3] + tgt_proj[row_a];
        out[row_a] = 1.f / (1.f + expf(-x));
    }
    if (pair && tid == 1) {
        const float x = wsb[0] + wsb[1] + wsb[2] + wsb[3] + tgt_proj[row_b];
        out[row_b] = 1.f / (1.f + expf(-x));
    }

    // ---- sweep ----
    float* la = out + (BB * TT) + (size_t)row_a * VV;
    const int h = (4 - (row_a & 3)) & 3;       // row_a's aligned head (floats)
    const int n = (VV - h) >> 2;               // aligned float4 groups (== for row_b)

    if (pair) {
        float* lb = la + VV;                   // head_b = h - 1 (h >= 1: row_a odd)
        for (int i = tid; i < n; i += 256) {
            const int v = h + (i << 2);
            const int s = (v - 1) & 31;
            const int w = (v - 1) >> 5;
            const uint2 bp0 = bmpre[w];
            const uint2 bp1 = bmpre[w + 1];    // sentinel-safe
            unsigned m5 = bp0.x >> s;
            if (s >= 28) m5 |= (bp1.x << (32 - s));
            m5 &= 31u;
            float2 e0 = make_float2(0.f, 0.f), e1 = e0, e2 = e0, e3 = e0, e4 = e0;
            if (m5) {
                ELEM(0, e0) ELEM(1, e1) ELEM(2, e2) ELEM(3, e3) ELEM(4, e4)
            }
            *(float4*)(la + v)     = make_float4(e1.x, e2.x, e3.x, e4.x);
            *(float4*)(lb + v - 1) = make_float4(e0.y, e1.y, e2.y, e3.y);
        }
        // heads (<=3 and <=2 scalars) and tails (<=2 and <=3 scalars)
        if (tid < h)     la[tid] = lut2(tid, bmpre, vals2).x;
        if (tid < h - 1) lb[tid] = lut2(tid, bmpre, vals2).y;
        const int ta = h + (n << 2);
        if (ta + tid < VV) la[ta + tid] = lut2(ta + tid, bmpre, vals2).x;
        const int tb = (h - 1) + (n << 2);
        if (tb + tid < VV) lb[tb + tid] = lut2(tb + tid, bmpre, vals2).y;
    } else {
        for (int i = tid; i < n; i += 256) {
            const int v = h + (i << 2);
            const int s = v & 31;
            const int w = v >> 5;
            const uint2 bp0 = bmpre[w];
            const uint2 bp1 = bmpre[w + 1];
            unsigned m5 = bp0.x >> s;          // 4-bit window, same machinery
            if (s >= 29) m5 |= (bp1.x << (32 - s));
            m5 &= 15u;
            float2 e0 = make_float2(0.f, 0.f), e1 = e0, e2 = e0, e3 = e0;
            if (m5) {
                ELEM(0, e0) ELEM(1, e1) ELEM(2, e2) ELEM(3, e3)
            }
            *(float4*)(la + v) = make_float4(e0.x, e1.x, e2.x, e3.x);
        }
        if (tid < h) la[tid] = lut2(tid, bmpre, vals2).x;
        const int ta = h + (n << 2);
        if (ta + tid < VV) la[ta + tid] = lut2(ta + tid, bmpre, vals2).x;
    }
}

extern "C" void kernel_launch(void* const* d_in, const int* in_sizes, int n_in,
                              void* d_out, int out_size, void* d_ws, size_t ws_size,
                              hipStream_t stream) {
    const int*   ids  = (const int*)d_in[0];    // [B,S]
    const float* attn = (const float*)d_in[1];  // [B,T,S]
    const float* src  = (const float*)d_in[2];  // [B,S,H]
    const float* tgt  = (const float*)d_in[3];  // [B,T,H]
    const float* W    = (const float*)d_in[4];  // [2H,1]
    const float* bp   = (const float*)d_in[5];  // [1]

    float* out = (float*)d_out;                 // [B*T (p_gen) | B*T*V]

    // ws layout (all 16B-aligned)
    float*          src_proj = (float*)d_ws;                          // 4096 f
    float*          tgt_proj = src_proj + BB * SS;                    // 2048 f
    uint2*          bmpre_g  = (uint2*)(tgt_proj + BB * TT);          // B*NWP uint2
    unsigned short* rank_g   = (unsigned short*)(bmpre_g + BB * NWP); // B*S u16

    prep_kernel<<<NPROJ + BB, 256, 0, stream>>>(
        src, tgt, W, bp, ids, src_proj, tgt_proj, bmpre_g, rank_g);
    row_kernel<<<BB * KPB, 256, 0, stream>>>(
        attn, src_proj, tgt_proj, bmpre_g, rank_g, out);
}

// Round 5
// 462.425 us; speedup vs baseline: 1.2623x; 1.0068x over previous
//
#include <hip/hip_runtime.h>
#include <math.h>

// Problem constants: B=4, T=512, S=1024, H=768, V=50257
#define BB 4
#define TT 512
#define SS 1024
#define HH 768
#define VV 50257
#define NW 1571            // ceil(V/32) bitmap words per batch
#define NWP 1600           // uint2 stride per batch for bmpre_g (>= NW+1)
#define NPROJ 1536         // proj blocks (6144 rows / 4 waves)
#define KPB 257            // row-blocks per batch: 255 pairs + 2 singles

// ---------------------------------------------------------------------------
// Kernel P (fused prep): blocks [0,1536) do projections; blocks [1536,1540)
// do per-batch bitmap/rank setup. bm and pre are written INTERLEAVED as
// uint2 (one ds_read_b64 fetches both in the row kernel). Sentinel word at
// index NW is zeroed (row kernel may read w+1 == NW).
// ---------------------------------------------------------------------------
__global__ __launch_bounds__(256) void prep_kernel(
    const float* __restrict__ src, const float* __restrict__ tgt,
    const float* __restrict__ W, const float* __restrict__ bptr,
    const int* __restrict__ ids,
    float* __restrict__ src_proj, float* __restrict__ tgt_proj,
    uint2* __restrict__ bmpre_g, unsigned short* __restrict__ rank_g)
{
    __shared__ unsigned bm[NW];
    __shared__ unsigned pre[NW];
    __shared__ unsigned scan[256];
    const int tid = threadIdx.x;

    if (blockIdx.x < NPROJ) {
        // ---- projection role: one wave per row, 4 rows/block ----
        const int wave = tid >> 6;
        const int lane = tid & 63;
        const int row  = blockIdx.x * 4 + wave;   // 0 .. 6143

        const float* vec;
        const float* w;
        if (row < BB * SS) { vec = src + (size_t)row * HH;            w = W; }
        else               { vec = tgt + (size_t)(row - BB*SS) * HH;  w = W + HH; }
        const float4* v4 = (const float4*)vec;
        const float4* w4 = (const float4*)w;

        float acc = 0.f;
#pragma unroll
        for (int k = 0; k < 3; ++k) {
            float4 a = v4[k * 64 + lane];
            float4 b = w4[k * 64 + lane];
            acc += a.x * b.x + a.y * b.y + a.z * b.z + a.w * b.w;
        }
#pragma unroll
        for (int off = 32; off > 0; off >>= 1) acc += __shfl_down(acc, off);
        if (lane == 0) {
            if (row < BB * SS) src_proj[row] = acc;
            else               tgt_proj[row - BB * SS] = acc + bptr[0];
        }
        return;
    }

    // ---- setup role: one block per batch ----
    const int b = blockIdx.x - NPROJ;

    for (int i = tid; i < NW; i += 256) bm[i] = 0u;
    __syncthreads();
    const int* idb = ids + b * SS;
    for (int s = tid; s < SS; s += 256) {
        const int v = idb[s];
        atomicOr(&bm[v >> 5], 1u << (v & 31));
    }
    __syncthreads();

    unsigned cnt[7];
    unsigned local = 0;
    const int w0 = tid * 7;                 // 256*7 = 1792 >= 1571
#pragma unroll
    for (int k = 0; k < 7; ++k) {
        const int w = w0 + k;
        cnt[k] = local;
        local += (w < NW) ? (unsigned)__popc(bm[w]) : 0u;
    }
    scan[tid] = local;
    __syncthreads();
    for (int off = 1; off < 256; off <<= 1) {
        const unsigned mine = scan[tid];
        const unsigned add  = (tid >= off) ? scan[tid - off] : 0u;
        __syncthreads();
        scan[tid] = mine + add;
        __syncthreads();
    }
    const unsigned excl = (tid > 0) ? scan[tid - 1] : 0u;
#pragma unroll
    for (int k = 0; k < 7; ++k) {
        const int w = w0 + k;
        if (w < NW) {
            const unsigned p = excl + cnt[k];
            pre[w] = p;
            bmpre_g[b * NWP + w] = make_uint2(bm[w], p);
        }
    }
    if (tid == 0) bmpre_g[b * NWP + NW] = make_uint2(0u, 0u);  // sentinel
    __syncthreads();
    for (int s = tid; s < SS; s += 256) {
        const int v = idb[s];
        const unsigned w = (unsigned)v >> 5, bit = (unsigned)v & 31u;
        const unsigned r = pre[w] + (unsigned)__popc(bm[w] & ((1u << bit) - 1u));
        rank_g[b * SS + s] = (unsigned short)r;
    }
}

// lut for one vocab index u: returns (row_a_val, row_b_val) or zeros.
__device__ __forceinline__ float2 lut2(int u, const uint2* __restrict__ bmpre,
                                       const float2* __restrict__ vals2)
{
    const uint2 bp = bmpre[u >> 5];
    const unsigned bt = (unsigned)u & 31u;
    if ((bp.x >> bt) & 1u)
        return vals2[bp.y + (unsigned)__popc(bp.x & ((1u << bt) - 1u))];
    return make_float2(0.f, 0.f);
}

// one element of the shared 5-wide window; t = s + j, word = w (+1 if t>=32)
#define ELEM(J, DST)                                                        \
    if (m5 & (1u << (J))) {                                                 \
        const unsigned t  = (unsigned)s + (J);                              \
        const unsigned bw = (t >= 32u) ? bp1.x : bp0.x;                     \
        const unsigned pw = (t >= 32u) ? bp1.y : bp0.y;                     \
        const unsigned bt = t & 31u;                                        \
        DST = vals2[pw + (unsigned)__popc(bw & ((1u << bt) - 1u))];         \
    }

// pair body: writes group IVAR of row_a (la) and row_b (lb, shifted -1)
#define PAIR_BODY(IVAR)                                                     \
    {                                                                       \
        const int v = h + ((IVAR) << 2);                                    \
        const int s = (v - 1) & 31;                                         \
        const int w = (v - 1) >> 5;                                         \
        const uint2 bp0 = bmpre[w];                                         \
        const uint2 bp1 = bmpre[w + 1];                                     \
        unsigned m5 = bp0.x >> s;                                           \
        if (s >= 28) m5 |= (bp1.x << (32 - s));                             \
        m5 &= 31u;                                                          \
        float2 e0 = make_float2(0.f,0.f), e1 = e0, e2 = e0, e3 = e0, e4 = e0;\
        if (m5) { ELEM(0, e0) ELEM(1, e1) ELEM(2, e2) ELEM(3, e3) ELEM(4, e4) } \
        *(float4*)(la + v)     = make_float4(e1.x, e2.x, e3.x, e4.x);       \
        *(float4*)(lb + v - 1) = make_float4(e0.y, e1.y, e2.y, e3.y);       \
    }

// single-row body
#define SINGLE_BODY(IVAR)                                                   \
    {                                                                       \
        const int v = h + ((IVAR) << 2);                                    \
        const int s = v & 31;                                               \
        const int w = v >> 5;                                               \
        const uint2 bp0 = bmpre[w];                                         \
        const uint2 bp1 = bmpre[w + 1];                                     \
        unsigned m5 = bp0.x >> s;                                           \
        if (s >= 29) m5 |= (bp1.x << (32 - s));                             \
        m5 &= 15u;                                                          \
        float2 e0 = make_float2(0.f,0.f), e1 = e0, e2 = e0, e3 = e0;        \
        if (m5) { ELEM(0, e0) ELEM(1, e1) ELEM(2, e2) ELEM(3, e3) }         \
        *(float4*)(la + v) = make_float4(e0.x, e1.x, e2.x, e3.x);           \
    }

// ---------------------------------------------------------------------------
// Kernel B: one block per ROW PAIR (identical to R4) except the SWEEP
// ITERATION ORDER: lane l of wave w handles groups 1024k + 256w + 64q + l
// (q = 0..3), so each wave writes a 4KB CONTIGUOUS window in 4 back-to-back
// fully-coalesced 1KB store instructions, and the block advances one 16KB
// contiguous window per outer iteration. DRAM-page bursts arrive clustered
// in time (fill-kernel-like) instead of spread across the whole sweep.
// ---------------------------------------------------------------------------
__global__ __launch_bounds__(256) void row_kernel(
    const float* __restrict__ attn,
    const float* __restrict__ src_proj,
    const float* __restrict__ tgt_proj,
    const uint2* __restrict__ bmpre_g,
    const unsigned short* __restrict__ rank_g,
    float* __restrict__ out)
{
    __shared__ uint2  bmpre[NW + 1];
    __shared__ float2 vals2[SS];
    __shared__ float  wsa[4], wsb[4];

    const int tid   = threadIdx.x;
    const int bid   = blockIdx.x;
    const int batch = bid / KPB;
    const int k     = bid - batch * KPB;
    const bool pair = (k > 0) && (k < 256);
    int row_a;
    if (k == 0)        row_a = batch * TT;            // single: row 0
    else if (k == 256) row_a = batch * TT + 511;      // single: row 511
    else               row_a = batch * TT + 2 * k - 1; // pair (odd, even)
    const int row_b = pair ? row_a + 1 : row_a;

    // ---- prologue: metadata + zeroed vals ----
    for (int i = tid; i < NW + 1; i += 256) bmpre[i] = bmpre_g[batch * NWP + i];
    ((float4*)vals2)[tid]       = make_float4(0.f, 0.f, 0.f, 0.f);
    ((float4*)vals2)[tid + 256] = make_float4(0.f, 0.f, 0.f, 0.f);
    __syncthreads();

    // ---- pass 1: vals2 accumulate + p_gen dots (ranks shared per batch) ----
    const float4*  aA  = (const float4*)(attn + (size_t)row_a * SS);
    const float4*  aB  = (const float4*)(attn + (size_t)row_b * SS);
    const float4*  sp4 = (const float4*)(src_proj + batch * SS);
    const ushort4* r4p = (const ushort4*)(rank_g + batch * SS);
    const float4  va = aA[tid];
    const float4  p  = sp4[tid];
    const ushort4 r  = r4p[tid];
    atomicAdd(&vals2[r.x].x, va.x);
    atomicAdd(&vals2[r.y].x, va.y);
    atomicAdd(&vals2[r.z].x, va.z);
    atomicAdd(&vals2[r.w].x, va.w);
    float accA = va.x * p.x + va.y * p.y + va.z * p.z + va.w * p.w;
    float accB = 0.f;
    if (pair) {
        const float4 vb = aB[tid];
        atomicAdd(&vals2[r.x].y, vb.x);
        atomicAdd(&vals2[r.y].y, vb.y);
        atomicAdd(&vals2[r.z].y, vb.z);
        atomicAdd(&vals2[r.w].y, vb.w);
        accB = vb.x * p.x + vb.y * p.y + vb.z * p.z + vb.w * p.w;
    }
#pragma unroll
    for (int off = 32; off > 0; off >>= 1) {
        accA += __shfl_down(accA, off);
        accB += __shfl_down(accB, off);
    }
    if ((tid & 63) == 0) { wsa[tid >> 6] = accA; wsb[tid >> 6] = accB; }
    __syncthreads();   // vals2 final + wsa/wsb visible
    if (tid == 0) {
        const float x = wsa[0] + wsa[1] + wsa[2] + wsa[3] + tgt_proj[row_a];
        out[row_a] = 1.f / (1.f + expf(-x));
    }
    if (pair && tid == 1) {
        const float x = wsb[0] + wsb[1] + wsb[2] + wsb[3] + tgt_proj[row_b];
        out[row_b] = 1.f / (1.f + expf(-x));
    }

    // ---- sweep ----
    float* la = out + (BB * TT) + (size_t)row_a * VV;
    const int h = (4 - (row_a & 3)) & 3;       // row_a's aligned head (floats)
    const int n = (VV - h) >> 2;               // aligned float4 groups

    const int wv = tid >> 6;                   // wave id 0..3
    const int ln = tid & 63;                   // lane id
    const int nK = n >> 10;                    // full 1024-group outer iters

    if (pair) {
        float* lb = la + VV;                   // head_b = h - 1 (h >= 1: row_a odd)
        for (int kk = 0; kk < nK; ++kk) {
            const int base = (kk << 10) + (wv << 8) + ln;
#pragma unroll
            for (int q = 0; q < 4; ++q) PAIR_BODY(base + (q << 6));
        }
        for (int i = (nK << 10) + tid; i < n; i += 256) PAIR_BODY(i);
        // heads (<=3 and <=2 scalars) and tails (<=2 and <=3 scalars)
        if (tid < h)     la[tid] = lut2(tid, bmpre, vals2).x;
        if (tid < h - 1) lb[tid] = lut2(tid, bmpre, vals2).y;
        const int ta = h + (n << 2);
        if (ta + tid < VV) la[ta + tid] = lut2(ta + tid, bmpre, vals2).x;
        const int tb = (h - 1) + (n << 2);
        if (tb + tid < VV) lb[tb + tid] = lut2(tb + tid, bmpre, vals2).y;
    } else {
        for (int kk = 0; kk < nK; ++kk) {
            const int base = (kk << 10) + (wv << 8) + ln;
#pragma unroll
            for (int q = 0; q < 4; ++q) SINGLE_BODY(base + (q << 6));
        }
        for (int i = (nK << 10) + tid; i < n; i += 256) SINGLE_BODY(i);
        if (tid < h) la[tid] = lut2(tid, bmpre, vals2).x;
        const int ta = h + (n << 2);
        if (ta + tid < VV) la[ta + tid] = lut2(ta + tid, bmpre, vals2).x;
    }
}

extern "C" void kernel_launch(void* const* d_in, const int* in_sizes, int n_in,
                              void* d_out, int out_size, void* d_ws, size_t ws_size,
                              hipStream_t stream) {
    const int*   ids  = (const int*)d_in[0];    // [B,S]
    const float* attn = (const float*)d_in[1];  // [B,T,S]
    const float* src  = (const float*)d_in[2];  // [B,S,H]
    const float* tgt  = (const float*)d_in[3];  // [B,T,H]
    const float* W    = (const float*)d_in[4];  // [2H,1]
    const float* bp   = (const float*)d_in[5];  // [1]

    float* out = (float*)d_out;                 // [B*T (p_gen) | B*T*V]

    // ws layout (all 16B-aligned)
    float*          src_proj = (float*)d_ws;                          // 4096 f
    float*          tgt_proj = src_proj + BB * SS;                    // 2048 f
    uint2*          bmpre_g  = (uint2*)(tgt_proj + BB * TT);          // B*NWP uint2
    unsigned short* rank_g   = (unsigned short*)(bmpre_g + BB * NWP); // B*S u16

    prep_kernel<<<NPROJ + BB, 256, 0, stream>>>(
        src, tgt, W, bp, ids, src_proj, tgt_proj, bmpre_g, rank_g);
    row_kernel<<<BB * KPB, 256, 0, stream>>>(
        attn, src_proj, tgt_proj, bmpre_g, rank_g, out);
}